// Round 8
// baseline (665.063 us; speedup 1.0000x reference)
//
#include <hip/hip_runtime.h>
#include <hip/hip_bf16.h>

// Problem constants
#define L1C 513
#define EMBC 64
#define VC 6
#define BC 128
#define NCOLS (L1C * VC)                  // 3078
#define NTC 64                            // n-columns per block tile
#define NTILES ((NCOLS + NTC - 1) / NTC)  // 49
#define NCHUNKR 31                        // real-path chunks
#define CSR 17                            // s per chunk (real path)

#define XELEMS ((size_t)L1C * BC * EMBC)
#define XBYTES (XELEMS * 2)               // 8,404,992
#define OUTELEMS ((size_t)BC * NCOLS)     // 393,984
#define PARTBYTES (OUTELEMS * 2)          // bf16 partials per chunk
#define WSLICE ((size_t)EMBC * NCOLS)     // one s-slice of W, in floats

typedef __attribute__((ext_vector_type(8))) short short8;
typedef __attribute__((ext_vector_type(4))) float f32x4;

__device__ __forceinline__ unsigned int pack_bf16x2(float a, float b) {
    __hip_bfloat16 ha = __float2bfloat16(a);
    __hip_bfloat16 hb = __float2bfloat16(b);
    unsigned short ua, ub;
    __builtin_memcpy(&ua, &ha, 2);
    __builtin_memcpy(&ub, &hb, 2);
    return (unsigned int)ua | ((unsigned int)ub << 16);
}

__device__ __forceinline__ unsigned short bf16bits(float a) {
    __hip_bfloat16 h = __float2bfloat16(a);
    unsigned short u;
    __builtin_memcpy(&u, &h, 2);
    return u;
}

// out[b][v][t] = bias[t][v]   (atomic-fallback path only)
__global__ void init_out_kernel(float* __restrict__ out, const float* __restrict__ bias) {
    int i = blockIdx.x * 256 + threadIdx.x;
    if (i >= (int)OUTELEMS) return;
    int r = i % NCOLS;
    int v = r / L1C;
    int t = r - v * L1C;
    out[i] = bias[t * VC + v];
}

// X[s][b][w] = bf16(emb[src[b,s], w]), linear layout
__global__ void build_x_kernel(const int* __restrict__ src, const float* __restrict__ emb,
                               unsigned short* __restrict__ X) {
    const int s = blockIdx.x;
    const int b = threadIdx.x >> 1;
    const int half = threadIdx.x & 1;
    const int tok = src[b * L1C + s];
    const float2* e = (const float2*)(emb + tok * EMBC + half * 32);
    unsigned int* row = (unsigned int*)(X + ((size_t)s * BC + b) * EMBC) + half * 16;
#pragma unroll
    for (int i = 0; i < 16; ++i) {
        float2 f = e[i];
        row[i] = pack_bf16x2(f.x, f.y);
    }
}

// ---- shared inner-loop macros (used by real gemm and probes) ----
#define ISSUEW(base, ss, farr)                                                   \
    {                                                                            \
        const int scl_ = ((ss) < L1C) ? (ss) : (L1C - 1);                        \
        const float* wb_ = (base) + ((size_t)scl_ * EMBC + wrow0) * NCOLS + nsafe; \
        _Pragma("unroll") for (int u_ = 0; u_ < 16; ++u_)                        \
            farr[u_] = wb_[(size_t)u_ * NCOLS];                                  \
    }

// dummy-W variant: address alternates between 2 L2-resident slices (s-dependent
// so the compiler cannot hoist the loads out of the s-loop)
#define ISSUEWD(base, ss, farr)                                                  \
    {                                                                            \
        const float* wb_ = (base) + ((size_t)((ss) & 1) * EMBC + wrow0) * NCOLS + nsafe; \
        _Pragma("unroll") for (int u_ = 0; u_ < 16; ++u_)                        \
            farr[u_] = wb_[(size_t)u_ * NCOLS];                                  \
    }

#define PACKW(ss, farr, buf)                                                     \
    {                                                                            \
        const bool act_ = (tcol <= (ss));                                        \
        char* dr_ = (char*)Blds[buf] + lane * 128;                               \
        _Pragma("unroll") for (int u_ = 0; u_ < 4; ++u_) {                       \
            float g0 = act_ ? farr[u_ * 4 + 0] : 0.f;                            \
            float g1 = act_ ? farr[u_ * 4 + 1] : 0.f;                            \
            float g2 = act_ ? farr[u_ * 4 + 2] : 0.f;                            \
            float g3 = act_ ? farr[u_ * 4 + 3] : 0.f;                            \
            uint2 pk_ = make_uint2(pack_bf16x2(g0, g1), pack_bf16x2(g2, g3));    \
            *(uint2*)(dr_ + ((2 * (wrow0 + u_ * 4)) ^ wswz)) = pk_;              \
        }                                                                        \
    }

#define ISSUEA(ss, aarr)                                                             \
    {                                                                                \
        const int scl_ = ((ss) < L1C) ? (ss) : (L1C - 1);                            \
        const unsigned short* xr_ = X + (size_t)scl_ * (BC * EMBC);                  \
        aarr[0] = *(const short8*)(xr_ + (wid * 32 + l15) * EMBC + h * 8);           \
        aarr[1] = *(const short8*)(xr_ + (wid * 32 + l15) * EMBC + 32 + h * 8);      \
        aarr[2] = *(const short8*)(xr_ + (wid * 32 + 16 + l15) * EMBC + h * 8);      \
        aarr[3] = *(const short8*)(xr_ + (wid * 32 + 16 + l15) * EMBC + 32 + h * 8); \
    }

#define MFMASTEP(aarr, buf)                                                                              \
    {                                                                                                    \
        _Pragma("unroll") for (int kk_ = 0; kk_ < 2; ++kk_) {                                            \
            const int foff_ = (kk_ * 64 + h * 16) ^ ((l15 & 7) << 4);                                    \
            _Pragma("unroll") for (int nt_ = 0; nt_ < 4; ++nt_) {                                        \
                short8 bb_ = *(const short8*)((const char*)Blds[buf] + (nt_ * 16 + l15) * 128 + foff_);  \
                acc[0][nt_] = __builtin_amdgcn_mfma_f32_16x16x32_bf16(aarr[kk_], bb_, acc[0][nt_], 0, 0, 0);     \
                acc[1][nt_] = __builtin_amdgcn_mfma_f32_16x16x32_bf16(aarr[2 + kk_], bb_, acc[1][nt_], 0, 0, 0); \
            }                                                                                            \
        }                                                                                                \
    }

// Real kernel: round-3 verified structure (93 us), 2-deep W pipe, 1 barrier/s.
template <bool PARTIAL>
__global__ __launch_bounds__(256) void gemm_tril_kernel(
    const float* __restrict__ Wt, const unsigned short* __restrict__ X,
    void* __restrict__ outp, int CS) {
    const int tile = blockIdx.x;
    const int chunk = blockIdx.y;
    const int n0 = tile * NTC;
    const int s0 = chunk * CS;
    const int sEnd = min(s0 + CS, L1C);

    __shared__ __align__(16) unsigned short Blds[2][NTC * EMBC];

    const int tid = threadIdx.x;
    const int wid = tid >> 6;
    const int lane = tid & 63;
    const int l15 = lane & 15;
    const int h = lane >> 4;

    const int n = n0 + lane;
    const int tcol = n / VC;
    const size_t nsafe = (n < NCOLS) ? (size_t)n : (size_t)(NCOLS - 1);
    const int wrow0 = wid * 16;
    const int wswz = (lane & 7) << 4;

    f32x4 acc[2][4];
#pragma unroll
    for (int i = 0; i < 2; ++i)
#pragma unroll
        for (int j = 0; j < 4; ++j) acc[i][j] = f32x4{0.f, 0.f, 0.f, 0.f};

    const int sBeg = max(s0, n0 / VC);

    if (sBeg < sEnd) {
        float fW0[16], fW1[16];
        short8 aC[4], aN[4];
        ISSUEW(Wt, sBeg, fW1);
        PACKW(sBeg, fW1, 0);
        ISSUEW(Wt, sBeg + 1, fW0);
        ISSUEA(sBeg, aC);
        __syncthreads();

        int s = sBeg, cur = 0;
        while (true) {
            ISSUEW(Wt, s + 2, fW1);
            ISSUEA(s + 1, aN);
            MFMASTEP(aC, cur);
            PACKW(s + 1, fW0, cur ^ 1);
            __syncthreads();
            cur ^= 1;
            if (++s >= sEnd) break;

            ISSUEW(Wt, s + 2, fW0);
            ISSUEA(s + 1, aC);
            MFMASTEP(aN, cur);
            PACKW(s + 1, fW1, cur ^ 1);
            __syncthreads();
            cur ^= 1;
            if (++s >= sEnd) break;
        }
    }

#pragma unroll
    for (int nt = 0; nt < 4; ++nt) {
        const int nn = n0 + nt * 16 + l15;
        if (nn >= NCOLS) continue;
        if (PARTIAL) {
            unsigned short* dst = (unsigned short*)outp + (size_t)chunk * OUTELEMS;
#pragma unroll
            for (int ms = 0; ms < 2; ++ms)
#pragma unroll
                for (int r = 0; r < 4; ++r) {
                    const int bi = wid * 32 + ms * 16 + h * 4 + r;
                    dst[(size_t)bi * NCOLS + nn] = bf16bits(acc[ms][nt][r]);
                }
        } else {
            float* dst = (float*)outp;
            const int t = nn / VC;
            const int v = nn - t * VC;
            const size_t obase = (size_t)v * L1C + t;
#pragma unroll
            for (int ms = 0; ms < 2; ++ms)
#pragma unroll
                for (int r = 0; r < 4; ++r) {
                    const int bi = wid * 32 + ms * 16 + h * 4 + r;
                    atomicAdd(dst + (size_t)bi * NCOLS + obase, acc[ms][nt][r]);
                }
        }
    }
}

// Diagnostic probe. MODE 1 = FULL (real W traffic), MODE 2 = NOW (L2-resident
// dummy W, same instruction stream). Repeated `reps` times so the dispatch is
// long enough to surface in the profiler top-5 with counters.
template <int MODE>
__global__ __launch_bounds__(256) void probe_kernel(
    const float* __restrict__ Wt, const float* __restrict__ Wd,
    const unsigned short* __restrict__ X,
    unsigned short* __restrict__ outp, int CS, int reps) {
    const int tile = blockIdx.x;
    const int chunk = blockIdx.y;
    const int n0 = tile * NTC;
    const int s0 = chunk * CS;
    const int sEnd = min(s0 + CS, L1C);

    __shared__ __align__(16) unsigned short Blds[2][NTC * EMBC];

    const int tid = threadIdx.x;
    const int wid = tid >> 6;
    const int lane = tid & 63;
    const int l15 = lane & 15;
    const int h = lane >> 4;

    const int n = n0 + lane;
    const int tcol = n / VC;
    const size_t nsafe = (n < NCOLS) ? (size_t)n : (size_t)(NCOLS - 1);
    const int wrow0 = wid * 16;
    const int wswz = (lane & 7) << 4;

    f32x4 acc[2][4];
#pragma unroll
    for (int i = 0; i < 2; ++i)
#pragma unroll
        for (int j = 0; j < 4; ++j) acc[i][j] = f32x4{0.f, 0.f, 0.f, 0.f};

    const int sBeg = max(s0, n0 / VC);

    for (int rep = 0; rep < reps; ++rep) {
        if (sBeg < sEnd) {
            float fW0[16], fW1[16];
            short8 aC[4], aN[4];
            if (MODE == 1) { ISSUEW(Wt, sBeg, fW1); } else { ISSUEWD(Wd, sBeg, fW1); }
            PACKW(sBeg, fW1, 0);
            if (MODE == 1) { ISSUEW(Wt, sBeg + 1, fW0); } else { ISSUEWD(Wd, sBeg + 1, fW0); }
            ISSUEA(sBeg, aC);
            __syncthreads();

            int s = sBeg, cur = 0;
            while (true) {
                if (MODE == 1) { ISSUEW(Wt, s + 2, fW1); } else { ISSUEWD(Wd, s + 2, fW1); }
                ISSUEA(s + 1, aN);
                MFMASTEP(aC, cur);
                PACKW(s + 1, fW0, cur ^ 1);
                __syncthreads();
                cur ^= 1;
                if (++s >= sEnd) break;

                if (MODE == 1) { ISSUEW(Wt, s + 2, fW0); } else { ISSUEWD(Wd, s + 2, fW0); }
                ISSUEA(s + 1, aC);
                MFMASTEP(aN, cur);
                PACKW(s + 1, fW1, cur ^ 1);
                __syncthreads();
                cur ^= 1;
                if (++s >= sEnd) break;
            }
        }
    }

    // keep everything live: write probe partials to scratch
#pragma unroll
    for (int nt = 0; nt < 4; ++nt) {
        const int nn = n0 + nt * 16 + l15;
        if (nn >= NCOLS) continue;
        unsigned short* dst = outp + (size_t)chunk * OUTELEMS;
#pragma unroll
        for (int ms = 0; ms < 2; ++ms)
#pragma unroll
            for (int r = 0; r < 4; ++r) {
                const int bi = wid * 32 + ms * 16 + h * 4 + r;
                dst[(size_t)bi * NCOLS + nn] = bf16bits(acc[ms][nt][r]);
            }
    }
}

// out[b][v][t] = bias[n] + sum_c bf16 partial[c][b][n],  n = t*6+v
__global__ void reduce_kernel(const unsigned short* __restrict__ partial,
                              const float* __restrict__ bias,
                              float* __restrict__ out, int nchunks) {
    int i4 = blockIdx.x * 256 + threadIdx.x;
    if (i4 >= (int)(OUTELEMS / 4)) return;
    const size_t base = (size_t)i4 * 4;
    float sum[4];
#pragma unroll
    for (int j = 0; j < 4; ++j) {
        int idx = (int)base + j;
        sum[j] = bias[idx % NCOLS];
    }
    for (int c = 0; c < nchunks; ++c) {
        const ushort4 p = *(const ushort4*)(partial + (size_t)c * OUTELEMS + base);
        unsigned int u0 = (unsigned int)p.x << 16, u1 = (unsigned int)p.y << 16;
        unsigned int u2 = (unsigned int)p.z << 16, u3 = (unsigned int)p.w << 16;
        float f0, f1, f2, f3;
        __builtin_memcpy(&f0, &u0, 4);
        __builtin_memcpy(&f1, &u1, 4);
        __builtin_memcpy(&f2, &u2, 4);
        __builtin_memcpy(&f3, &u3, 4);
        sum[0] += f0;
        sum[1] += f1;
        sum[2] += f2;
        sum[3] += f3;
    }
#pragma unroll
    for (int j = 0; j < 4; ++j) {
        int idx = (int)base + j;
        int b = idx / NCOLS;
        int nn = idx - b * NCOLS;
        int t = nn / VC;
        int v = nn - t * VC;
        out[(size_t)b * NCOLS + (size_t)v * L1C + t] = sum[j];
    }
}

extern "C" void kernel_launch(void* const* d_in, const int* in_sizes, int n_in,
                              void* d_out, int out_size, void* d_ws, size_t ws_size,
                              hipStream_t stream) {
    const int* src = (const int*)d_in[0];
    const float* emb = (const float*)d_in[1];
    const float* wt = (const float*)d_in[2];
    const float* bias = (const float*)d_in[3];
    float* out = (float*)d_out;
    unsigned short* X = (unsigned short*)d_ws;

    build_x_kernel<<<L1C, 256, 0, stream>>>(src, emb, X);

    const size_t realPart = (size_t)NCHUNKR * PARTBYTES;
    const size_t probePart = realPart;
    const size_t dummyW = 2 * WSLICE * 4;
    const size_t need = XBYTES + realPart + probePart + dummyW;

    if (ws_size >= need) {
        unsigned short* partial = (unsigned short*)((char*)d_ws + XBYTES);
        unsigned short* ppart = (unsigned short*)((char*)d_ws + XBYTES + realPart);
        const float* wdummy = (const float*)((char*)d_ws + XBYTES + realPart + probePart);

        dim3 grid(NTILES, NCHUNKR);
        gemm_tril_kernel<true><<<grid, 256, 0, stream>>>(wt, X, (void*)partial, CSR);
        reduce_kernel<<<(int)((OUTELEMS / 4 + 255) / 256), 256, 0, stream>>>(partial, bias, out, NCHUNKR);

        // ---- diagnostic probes (write to scratch; do not affect output) ----
        probe_kernel<1><<<grid, 256, 0, stream>>>(wt, wdummy, X, ppart, CSR, 4);
        probe_kernel<2><<<grid, 256, 0, stream>>>(wt, wdummy, X, ppart, CSR, 8);
    } else if (ws_size >= XBYTES + 2 * PARTBYTES) {
        int nchunks = (int)((ws_size - XBYTES) / PARTBYTES);
        if (nchunks > NCHUNKR) nchunks = NCHUNKR;
        int CS = (L1C + nchunks - 1) / nchunks;
        nchunks = (L1C + CS - 1) / CS;
        unsigned short* partial = (unsigned short*)((char*)d_ws + XBYTES);
        dim3 grid(NTILES, nchunks);
        gemm_tril_kernel<true><<<grid, 256, 0, stream>>>(wt, X, (void*)partial, CS);
        reduce_kernel<<<(int)((OUTELEMS / 4 + 255) / 256), 256, 0, stream>>>(partial, bias, out, nchunks);
    } else {
        init_out_kernel<<<(int)((OUTELEMS + 255) / 256), 256, 0, stream>>>(out, bias);
        dim3 grid(NTILES, 17);
        gemm_tril_kernel<false><<<grid, 256, 0, stream>>>(wt, X, (void*)out, 31);
    }
}

// Round 9
// 191.006 us; speedup vs baseline: 3.4819x; 3.4819x over previous
//
#include <hip/hip_runtime.h>
#include <hip/hip_bf16.h>

// Problem constants
#define L1C 513
#define EMBC 64
#define VC 6
#define BC 128
#define NCOLS (L1C * VC)                  // 3078
#define NTC 64                            // n-columns per block tile (4 waves x 16)
#define NTILES ((NCOLS + NTC - 1) / NTC)  // 49
#define CSC 12                            // s per chunk (split-K)
#define NCHUNK ((L1C + CSC - 1) / CSC)    // 43

#define XELEMS ((size_t)L1C * BC * EMBC)
#define XBYTES (XELEMS * 2)               // 8,404,992
#define OUTELEMS ((size_t)BC * NCOLS)     // 393,984
#define PARTBYTES (OUTELEMS * 2)          // bf16 partials per chunk
#define WSL ((size_t)EMBC * NCOLS)        // W slice stride in floats

typedef __attribute__((ext_vector_type(8))) short short8;
typedef __attribute__((ext_vector_type(4))) float f32x4;

__device__ __forceinline__ unsigned int pack_bf16x2(float a, float b) {
    __hip_bfloat16 ha = __float2bfloat16(a);
    __hip_bfloat16 hb = __float2bfloat16(b);
    unsigned short ua, ub;
    __builtin_memcpy(&ua, &ha, 2);
    __builtin_memcpy(&ub, &hb, 2);
    return (unsigned int)ua | ((unsigned int)ub << 16);
}

__device__ __forceinline__ unsigned short bf16bits(float a) {
    __hip_bfloat16 h = __float2bfloat16(a);
    unsigned short u;
    __builtin_memcpy(&u, &h, 2);
    return u;
}

// out[b][v][t] = bias[t][v]   (atomic-fallback path only)
__global__ void init_out_kernel(float* __restrict__ out, const float* __restrict__ bias) {
    int i = blockIdx.x * 256 + threadIdx.x;
    if (i >= (int)OUTELEMS) return;
    int r = i % NCOLS;
    int v = r / L1C;
    int t = r - v * L1C;
    out[i] = bias[t * VC + v];
}

// X[s][b][w] = bf16(emb[src[b,s], w]), linear layout
__global__ void build_x_kernel(const int* __restrict__ src, const float* __restrict__ emb,
                               unsigned short* __restrict__ X) {
    const int s = blockIdx.x;
    const int b = threadIdx.x >> 1;
    const int half = threadIdx.x & 1;
    const int tok = src[b * L1C + s];
    const float2* e = (const float2*)(emb + tok * EMBC + half * 32);
    unsigned int* row = (unsigned int*)(X + ((size_t)s * BC + b) * EMBC) + half * 16;
#pragma unroll
    for (int i = 0; i < 16; ++i) {
        float2 f = e[i];
        row[i] = pack_bf16x2(f.x, f.y);
    }
}

// Direct-to-fragment GEMM: no LDS, no barriers.
// Wave wv of block (tile,chunk) computes C[128 b x 16 n] for n = tile*64 + wv*16 + l15,
// summing over s in [max(s0, tmin) .. sEnd). B-frag (W) loaded straight from global:
// lane (h,l15) reads W[(s*64 + kk*32 + h*8 + j) * NCOLS + n], masked by (t(n) <= s),
// packed to bf16 in-register. A-frag read straight from global X (L1/L2-hot).
template <bool PARTIAL>
__global__ __launch_bounds__(256) void gemm_direct_kernel(
    const float* __restrict__ Wt, const unsigned short* __restrict__ X,
    void* __restrict__ outp, int CS) {
    const int tile = blockIdx.x;
    const int chunk = blockIdx.y;
    const int n0 = tile * NTC;
    const int s0 = chunk * CS;
    const int sEnd = min(s0 + CS, L1C);
    const int sBeg = max(s0, n0 / VC);
    if (sBeg >= sEnd) return;  // dead block; reduce skips these chunks

    const int tid = threadIdx.x;
    const int wv = tid >> 6;
    const int lane = tid & 63;
    const int l15 = lane & 15;
    const int h = lane >> 4;

    const int n = n0 + wv * 16 + l15;         // this lane's output column
    const int tcol = n / VC;                  // pad cols (n>=NCOLS) -> tcol>=513 -> masked
    const int nsafe = (n < NCOLS) ? n : (NCOLS - 1);

    f32x4 acc[8];
#pragma unroll
    for (int i = 0; i < 8; ++i) acc[i] = f32x4{0.f, 0.f, 0.f, 0.f};

// issue 16 W dwords for one s-slice from stepping per-lane pointer p
#define ISSUEWP(p, farr)                                                  \
    {                                                                     \
        _Pragma("unroll") for (int j_ = 0; j_ < 8; ++j_)                  \
            farr[j_] = (p)[(size_t)j_ * NCOLS];                           \
        _Pragma("unroll") for (int j_ = 0; j_ < 8; ++j_)                  \
            farr[8 + j_] = (p)[(size_t)(32 + j_) * NCOLS];                \
    }

// mask + pack to B-frags, load A-frags from X, 16 MFMAs
#define COMPUTE(ss, farr)                                                             \
    {                                                                                 \
        const bool act_ = (tcol <= (ss));                                             \
        unsigned int bu_[8];                                                          \
        _Pragma("unroll") for (int i_ = 0; i_ < 4; ++i_) {                            \
            float g0 = act_ ? farr[2 * i_] : 0.f;                                     \
            float g1 = act_ ? farr[2 * i_ + 1] : 0.f;                                 \
            float g2 = act_ ? farr[8 + 2 * i_] : 0.f;                                 \
            float g3 = act_ ? farr[8 + 2 * i_ + 1] : 0.f;                             \
            bu_[i_] = pack_bf16x2(g0, g1);                                            \
            bu_[4 + i_] = pack_bf16x2(g2, g3);                                        \
        }                                                                             \
        short8 b0_, b1_;                                                              \
        __builtin_memcpy(&b0_, &bu_[0], 16);                                          \
        __builtin_memcpy(&b1_, &bu_[4], 16);                                          \
        const unsigned short* xr_ = X + (size_t)(ss) * (BC * EMBC) + l15 * EMBC + h * 8; \
        _Pragma("unroll") for (int mt_ = 0; mt_ < 8; ++mt_) {                         \
            short8 a0_ = *(const short8*)(xr_ + mt_ * 16 * EMBC);                     \
            short8 a1_ = *(const short8*)(xr_ + mt_ * 16 * EMBC + 32);                \
            acc[mt_] = __builtin_amdgcn_mfma_f32_16x16x32_bf16(a0_, b0_, acc[mt_], 0, 0, 0); \
            acc[mt_] = __builtin_amdgcn_mfma_f32_16x16x32_bf16(a1_, b1_, acc[mt_], 0, 0, 0); \
        }                                                                             \
    }

    {
        float fwA[16], fwB[16];
        const float* wp = Wt + (size_t)sBeg * WSL + (size_t)(h * 8) * NCOLS + nsafe;
        ISSUEWP(wp, fwA);
        wp += WSL;

        int s = sBeg;
        while (true) {
            if (s + 1 < sEnd) { ISSUEWP(wp, fwB); wp += WSL; }
            COMPUTE(s, fwA);
            if (++s >= sEnd) break;

            if (s + 1 < sEnd) { ISSUEWP(wp, fwA); wp += WSL; }
            COMPUTE(s, fwB);
            if (++s >= sEnd) break;
        }
    }

    // epilogue — C/D layout (verified): col = l15 (this lane's n), row-in-16 = h*4 + r
    if (n < NCOLS) {
        if (PARTIAL) {
            unsigned short* dst = (unsigned short*)outp + (size_t)chunk * OUTELEMS + n;
#pragma unroll
            for (int mt = 0; mt < 8; ++mt)
#pragma unroll
                for (int r = 0; r < 4; ++r) {
                    const int bi = mt * 16 + h * 4 + r;
                    dst[(size_t)bi * NCOLS] = bf16bits(acc[mt][r]);
                }
        } else {
            float* dst = (float*)outp;
            const int t = n / VC;
            const int v = n - t * VC;
            const size_t obase = (size_t)v * L1C + t;
#pragma unroll
            for (int mt = 0; mt < 8; ++mt)
#pragma unroll
                for (int r = 0; r < 4; ++r) {
                    const int bi = mt * 16 + h * 4 + r;
                    atomicAdd(dst + (size_t)bi * NCOLS + obase, acc[mt][r]);
                }
        }
    }
#undef ISSUEWP
#undef COMPUTE
}

// out[b][v][t] = bias[n] + sum_{c>=cfirst(tile(n))} bf16 partial[c][b][n],  n = t*6+v
__global__ void reduce_kernel(const unsigned short* __restrict__ partial,
                              const float* __restrict__ bias,
                              float* __restrict__ out, int nchunks, int CS) {
    int i4 = blockIdx.x * 256 + threadIdx.x;
    if (i4 >= (int)(OUTELEMS / 4)) return;
    const size_t base = (size_t)i4 * 4;
    float sum[4];
    int cf[4];
    int cmin = 1 << 30;
#pragma unroll
    for (int j = 0; j < 4; ++j) {
        int idx = (int)base + j;
        int nn = idx % NCOLS;
        sum[j] = bias[nn];
        int tl = nn >> 6;              // tile = nn / NTC (NTC=64)
        int tmin = (tl << 6) / VC;     // first live s for this tile
        cf[j] = tmin / CS;             // first live chunk (matches gemm's sBeg rule)
        cmin = min(cmin, cf[j]);
    }
    for (int c = cmin; c < nchunks; ++c) {
        const ushort4 p = *(const ushort4*)(partial + (size_t)c * OUTELEMS + base);
        unsigned int u0 = (unsigned int)p.x << 16, u1 = (unsigned int)p.y << 16;
        unsigned int u2 = (unsigned int)p.z << 16, u3 = (unsigned int)p.w << 16;
        float f0, f1, f2, f3;
        __builtin_memcpy(&f0, &u0, 4);
        __builtin_memcpy(&f1, &u1, 4);
        __builtin_memcpy(&f2, &u2, 4);
        __builtin_memcpy(&f3, &u3, 4);
        if (c >= cf[0]) sum[0] += f0;
        if (c >= cf[1]) sum[1] += f1;
        if (c >= cf[2]) sum[2] += f2;
        if (c >= cf[3]) sum[3] += f3;
    }
#pragma unroll
    for (int j = 0; j < 4; ++j) {
        int idx = (int)base + j;
        int b = idx / NCOLS;
        int nn = idx - b * NCOLS;
        int t = nn / VC;
        int v = nn - t * VC;
        out[(size_t)b * NCOLS + (size_t)v * L1C + t] = sum[j];
    }
}

extern "C" void kernel_launch(void* const* d_in, const int* in_sizes, int n_in,
                              void* d_out, int out_size, void* d_ws, size_t ws_size,
                              hipStream_t stream) {
    const int* src = (const int*)d_in[0];
    const float* emb = (const float*)d_in[1];
    const float* wt = (const float*)d_in[2];
    const float* bias = (const float*)d_in[3];
    float* out = (float*)d_out;
    unsigned short* X = (unsigned short*)d_ws;

    build_x_kernel<<<L1C, 256, 0, stream>>>(src, emb, X);

    if (ws_size >= XBYTES + (size_t)NCHUNK * PARTBYTES) {
        unsigned short* partial = (unsigned short*)((char*)d_ws + XBYTES);
        dim3 grid(NTILES, NCHUNK);
        gemm_direct_kernel<true><<<grid, 256, 0, stream>>>(wt, X, (void*)partial, CSC);
        reduce_kernel<<<(int)((OUTELEMS / 4 + 255) / 256), 256, 0, stream>>>(partial, bias, out, NCHUNK, CSC);
    } else if (ws_size >= XBYTES + 2 * PARTBYTES) {
        int nchunks = (int)((ws_size - XBYTES) / PARTBYTES);
        if (nchunks > NCHUNK) nchunks = NCHUNK;
        int CS = (L1C + nchunks - 1) / nchunks;
        nchunks = (L1C + CS - 1) / CS;
        unsigned short* partial = (unsigned short*)((char*)d_ws + XBYTES);
        dim3 grid(NTILES, nchunks);
        gemm_direct_kernel<true><<<grid, 256, 0, stream>>>(wt, X, (void*)partial, CS);
        reduce_kernel<<<(int)((OUTELEMS / 4 + 255) / 256), 256, 0, stream>>>(partial, bias, out, nchunks, CS);
    } else {
        init_out_kernel<<<(int)((OUTELEMS + 255) / 256), 256, 0, stream>>>(out, bias);
        dim3 grid(NTILES, 17);
        gemm_direct_kernel<false><<<grid, 256, 0, stream>>>(wt, X, (void*)out, 31);
    }
}

// Round 10
// 103.446 us; speedup vs baseline: 6.4291x; 1.8464x over previous
//
#include <hip/hip_runtime.h>
#include <hip/hip_bf16.h>

// Problem constants
#define L1C 513
#define EMBC 64
#define VC 6
#define BC 128
#define NCOLS (L1C * VC)                  // 3078
#define NTC 64                            // n-columns per block tile
#define NTILES ((NCOLS + NTC - 1) / NTC)  // 49
#define CSC 8                             // s per chunk (split-K)
#define NCHUNK ((L1C + CSC - 1) / CSC)    // 65

#define XELEMS ((size_t)L1C * BC * EMBC)
#define XBYTES (XELEMS * 2)               // 8,404,992
#define OUTELEMS ((size_t)BC * NCOLS)     // 393,984
#define PARTBYTES (OUTELEMS * 2)          // bf16 partials per chunk

typedef __attribute__((ext_vector_type(8))) short short8;
typedef __attribute__((ext_vector_type(4))) float f32x4;

__device__ __forceinline__ unsigned int pack_bf16x2(float a, float b) {
    __hip_bfloat16 ha = __float2bfloat16(a);
    __hip_bfloat16 hb = __float2bfloat16(b);
    unsigned short ua, ub;
    __builtin_memcpy(&ua, &ha, 2);
    __builtin_memcpy(&ub, &hb, 2);
    return (unsigned int)ua | ((unsigned int)ub << 16);
}

__device__ __forceinline__ unsigned short bf16bits(float a) {
    __hip_bfloat16 h = __float2bfloat16(a);
    unsigned short u;
    __builtin_memcpy(&u, &h, 2);
    return u;
}

// out[b][v][t] = bias[t][v]   (atomic-fallback path only)
__global__ void init_out_kernel(float* __restrict__ out, const float* __restrict__ bias) {
    int i = blockIdx.x * 256 + threadIdx.x;
    if (i >= (int)OUTELEMS) return;
    int r = i % NCOLS;
    int v = r / L1C;
    int t = r - v * L1C;
    out[i] = bias[t * VC + v];
}

// X[s][b][w] = bf16(emb[src[b,s], w]), linear layout
__global__ void build_x_kernel(const int* __restrict__ src, const float* __restrict__ emb,
                               unsigned short* __restrict__ X) {
    const int s = blockIdx.x;
    const int b = threadIdx.x >> 1;
    const int half = threadIdx.x & 1;
    const int tok = src[b * L1C + s];
    const float2* e = (const float2*)(emb + tok * EMBC + half * 32);
    unsigned int* row = (unsigned int*)(X + ((size_t)s * BC + b) * EMBC) + half * 16;
#pragma unroll
    for (int i = 0; i < 16; ++i) {
        float2 f = e[i];
        row[i] = pack_bf16x2(f.x, f.y);
    }
}

// Per (n-tile, s-chunk) block: C[128 x 64] = sum_{s in chunk, s>=t} X_s(128x64) @ W_s(64x64)
// Round-3 structure; register diet (no A-prefetch set) for 4+ blocks/CU residency;
// A issued BEFORE W each iter so the MFMA vmcnt-wait keeps the W prefetch in flight.
// XCD tile-grouping swizzle: consecutive tiles of a chunk share an XCD (DRAM row locality).
template <bool PARTIAL>
__global__ __launch_bounds__(256, 4) void gemm_tril_kernel(
    const float* __restrict__ Wt, const unsigned short* __restrict__ X,
    void* __restrict__ outp, int CS) {
    // bijective XCD grouping over 49 tiles: q=6, r=1 (m204 form)
    const int xb = blockIdx.x;
    const int xcd = xb & 7;
    const int pos = xb >> 3;
    const int tile = ((xcd == 0) ? 0 : (7 + (xcd - 1) * 6)) + pos;

    const int chunk = blockIdx.y;
    const int n0 = tile * NTC;
    const int s0 = chunk * CS;
    const int sEnd = min(s0 + CS, L1C);
    const int sBeg = max(s0, n0 / VC);
    if (sBeg >= sEnd) return;  // dead block; reduce skips these chunks

    __shared__ __align__(16) unsigned short Blds[2][NTC * EMBC];  // 2 x 8KB

    const int tid = threadIdx.x;
    const int wid = tid >> 6;
    const int lane = tid & 63;
    const int l15 = lane & 15;
    const int h = lane >> 4;

    const int n = n0 + lane;
    const int tcol = n / VC;  // pad columns (n>=NCOLS) -> tcol>=513 -> always masked
    const size_t nsafe = (n < NCOLS) ? (size_t)n : (size_t)(NCOLS - 1);
    const int wrow0 = wid * 16;
    const int wswz = (lane & 7) << 4;

    f32x4 acc[2][4];
#pragma unroll
    for (int i = 0; i < 2; ++i)
#pragma unroll
        for (int j = 0; j < 4; ++j) acc[i][j] = f32x4{0.f, 0.f, 0.f, 0.f};

#define ISSUEW(ss, farr)                                                         \
    {                                                                            \
        const int scl_ = ((ss) < L1C) ? (ss) : (L1C - 1);                        \
        const float* wb_ = Wt + ((size_t)scl_ * EMBC + wrow0) * NCOLS + nsafe;   \
        _Pragma("unroll") for (int u_ = 0; u_ < 16; ++u_)                        \
            farr[u_] = wb_[(size_t)u_ * NCOLS];                                  \
    }

#define PACKW(ss, farr, buf)                                                     \
    {                                                                            \
        const bool act_ = (tcol <= (ss));                                        \
        char* dr_ = (char*)Blds[buf] + lane * 128;                               \
        _Pragma("unroll") for (int u_ = 0; u_ < 4; ++u_) {                       \
            float g0 = act_ ? farr[u_ * 4 + 0] : 0.f;                            \
            float g1 = act_ ? farr[u_ * 4 + 1] : 0.f;                            \
            float g2 = act_ ? farr[u_ * 4 + 2] : 0.f;                            \
            float g3 = act_ ? farr[u_ * 4 + 3] : 0.f;                            \
            uint2 pk_ = make_uint2(pack_bf16x2(g0, g1), pack_bf16x2(g2, g3));    \
            *(uint2*)(dr_ + ((2 * (wrow0 + u_ * 4)) ^ wswz)) = pk_;              \
        }                                                                        \
    }

#define ISSUEA(ss, aarr)                                                             \
    {                                                                                \
        const unsigned short* xr_ = X + (size_t)(ss) * (BC * EMBC);                  \
        aarr[0] = *(const short8*)(xr_ + (wid * 32 + l15) * EMBC + h * 8);           \
        aarr[1] = *(const short8*)(xr_ + (wid * 32 + l15) * EMBC + 32 + h * 8);      \
        aarr[2] = *(const short8*)(xr_ + (wid * 32 + 16 + l15) * EMBC + h * 8);      \
        aarr[3] = *(const short8*)(xr_ + (wid * 32 + 16 + l15) * EMBC + 32 + h * 8); \
    }

#define MFMASTEP(aarr, buf)                                                                              \
    {                                                                                                    \
        _Pragma("unroll") for (int kk_ = 0; kk_ < 2; ++kk_) {                                            \
            const int foff_ = (kk_ * 64 + h * 16) ^ ((l15 & 7) << 4);                                    \
            _Pragma("unroll") for (int nt_ = 0; nt_ < 4; ++nt_) {                                        \
                short8 bb_ = *(const short8*)((const char*)Blds[buf] + (nt_ * 16 + l15) * 128 + foff_);  \
                acc[0][nt_] = __builtin_amdgcn_mfma_f32_16x16x32_bf16(aarr[kk_], bb_, acc[0][nt_], 0, 0, 0);     \
                acc[1][nt_] = __builtin_amdgcn_mfma_f32_16x16x32_bf16(aarr[2 + kk_], bb_, acc[1][nt_], 0, 0, 0); \
            }                                                                                            \
        }                                                                                                \
    }

    {
        float fW0[16], fW1[16];
        short8 aC[4];
        // prologue: stage B(sBeg) via fW1's storage; 1-ahead W prefetch into fW0
        ISSUEW(sBeg, fW1);
        PACKW(sBeg, fW1, 0);
        ISSUEW(sBeg + 1, fW0);
        __syncthreads();

        int s = sBeg, cur = 0;
        while (true) {
            // even iter: A first (so MFMA wait leaves W in flight), then W(s+2)
            ISSUEA(s, aC);
            ISSUEW(s + 2, fW1);
            MFMASTEP(aC, cur);
            PACKW(s + 1, fW0, cur ^ 1);
            __syncthreads();
            cur ^= 1;
            if (++s >= sEnd) break;

            // odd iter: consume fW1
            ISSUEA(s, aC);
            ISSUEW(s + 2, fW0);
            MFMASTEP(aC, cur);
            PACKW(s + 1, fW1, cur ^ 1);
            __syncthreads();
            cur ^= 1;
            if (++s >= sEnd) break;
        }
    }

    // epilogue — C/D layout (verified): col = l15 (n), row-in-16 = h*4 + reg
#pragma unroll
    for (int nt = 0; nt < 4; ++nt) {
        const int nn = n0 + nt * 16 + l15;
        if (nn >= NCOLS) continue;
        if (PARTIAL) {
            unsigned short* dst = (unsigned short*)outp + (size_t)chunk * OUTELEMS;
#pragma unroll
            for (int ms = 0; ms < 2; ++ms)
#pragma unroll
                for (int r = 0; r < 4; ++r) {
                    const int bi = wid * 32 + ms * 16 + h * 4 + r;
                    dst[(size_t)bi * NCOLS + nn] = bf16bits(acc[ms][nt][r]);
                }
        } else {
            float* dst = (float*)outp;
            const int t = nn / VC;
            const int v = nn - t * VC;
            const size_t obase = (size_t)v * L1C + t;
#pragma unroll
            for (int ms = 0; ms < 2; ++ms)
#pragma unroll
                for (int r = 0; r < 4; ++r) {
                    const int bi = wid * 32 + ms * 16 + h * 4 + r;
                    atomicAdd(dst + (size_t)bi * NCOLS + obase, acc[ms][nt][r]);
                }
        }
    }
#undef ISSUEW
#undef PACKW
#undef ISSUEA
#undef MFMASTEP
}

// out[b][v][t] = bias[n] + sum_{c>=cfirst(tile(n))} bf16 partial[c][b][n],  n = t*6+v
__global__ void reduce_kernel(const unsigned short* __restrict__ partial,
                              const float* __restrict__ bias,
                              float* __restrict__ out, int nchunks, int CS) {
    int i4 = blockIdx.x * 256 + threadIdx.x;
    if (i4 >= (int)(OUTELEMS / 4)) return;
    const size_t base = (size_t)i4 * 4;
    float sum[4];
    int cf[4];
    int cmin = 1 << 30;
#pragma unroll
    for (int j = 0; j < 4; ++j) {
        int idx = (int)base + j;
        int nn = idx % NCOLS;
        sum[j] = bias[nn];
        int tl = nn >> 6;              // tile = nn / NTC (NTC=64)
        int tmin = (tl << 6) / VC;     // first live s for this tile
        cf[j] = tmin / CS;             // first live chunk (matches gemm's sBeg rule)
        cmin = min(cmin, cf[j]);
    }
    for (int c = cmin; c < nchunks; ++c) {
        const ushort4 p = *(const ushort4*)(partial + (size_t)c * OUTELEMS + base);
        unsigned int u0 = (unsigned int)p.x << 16, u1 = (unsigned int)p.y << 16;
        unsigned int u2 = (unsigned int)p.z << 16, u3 = (unsigned int)p.w << 16;
        float f0, f1, f2, f3;
        __builtin_memcpy(&f0, &u0, 4);
        __builtin_memcpy(&f1, &u1, 4);
        __builtin_memcpy(&f2, &u2, 4);
        __builtin_memcpy(&f3, &u3, 4);
        if (c >= cf[0]) sum[0] += f0;
        if (c >= cf[1]) sum[1] += f1;
        if (c >= cf[2]) sum[2] += f2;
        if (c >= cf[3]) sum[3] += f3;
    }
#pragma unroll
    for (int j = 0; j < 4; ++j) {
        int idx = (int)base + j;
        int b = idx / NCOLS;
        int nn = idx - b * NCOLS;
        int t = nn / VC;
        int v = nn - t * VC;
        out[(size_t)b * NCOLS + (size_t)v * L1C + t] = sum[j];
    }
}

extern "C" void kernel_launch(void* const* d_in, const int* in_sizes, int n_in,
                              void* d_out, int out_size, void* d_ws, size_t ws_size,
                              hipStream_t stream) {
    const int* src = (const int*)d_in[0];
    const float* emb = (const float*)d_in[1];
    const float* wt = (const float*)d_in[2];
    const float* bias = (const float*)d_in[3];
    float* out = (float*)d_out;
    unsigned short* X = (unsigned short*)d_ws;

    build_x_kernel<<<L1C, 256, 0, stream>>>(src, emb, X);

    if (ws_size >= XBYTES + (size_t)NCHUNK * PARTBYTES) {
        unsigned short* partial = (unsigned short*)((char*)d_ws + XBYTES);
        dim3 grid(NTILES, NCHUNK);   // blockIdx.x is XCD-swizzled inside the kernel
        gemm_tril_kernel<true><<<grid, 256, 0, stream>>>(wt, X, (void*)partial, CSC);
        reduce_kernel<<<(int)((OUTELEMS / 4 + 255) / 256), 256, 0, stream>>>(partial, bias, out, NCHUNK, CSC);
    } else if (ws_size >= XBYTES + 2 * PARTBYTES) {
        int nchunks = (int)((ws_size - XBYTES) / PARTBYTES);
        if (nchunks > NCHUNK) nchunks = NCHUNK;
        int CS = (L1C + nchunks - 1) / nchunks;
        nchunks = (L1C + CS - 1) / CS;
        unsigned short* partial = (unsigned short*)((char*)d_ws + XBYTES);
        dim3 grid(NTILES, nchunks);
        gemm_tril_kernel<true><<<grid, 256, 0, stream>>>(wt, X, (void*)partial, CS);
        reduce_kernel<<<(int)((OUTELEMS / 4 + 255) / 256), 256, 0, stream>>>(partial, bias, out, nchunks, CS);
    } else {
        init_out_kernel<<<(int)((OUTELEMS + 255) / 256), 256, 0, stream>>>(out, bias);
        dim3 grid(NTILES, 17);
        gemm_tril_kernel<false><<<grid, 256, 0, stream>>>(wt, X, (void*)out, 31);
    }
}

// Round 11
// 86.479 us; speedup vs baseline: 7.6904x; 1.1962x over previous
//
#include <hip/hip_runtime.h>
#include <hip/hip_bf16.h>

// Problem constants
#define L1C 513
#define EMBC 64
#define VC 6
#define BC 128
#define NCOLS (L1C * VC)                  // 3078
#define NTC 64                            // n-columns per block tile
#define NTILES ((NCOLS + NTC - 1) / NTC)  // 49
#define CSC 14                            // s per chunk (split-K): ~1010 live blocks ~= 4/CU
#define NCHUNK ((L1C + CSC - 1) / CSC)    // 37

#define XELEMS ((size_t)L1C * BC * EMBC)
#define XBYTES (XELEMS * 2)               // 8,404,992
#define OUTELEMS ((size_t)BC * NCOLS)     // 393,984
#define PARTBYTES (OUTELEMS * 2)          // bf16 partials per chunk

typedef __attribute__((ext_vector_type(8))) short short8;
typedef __attribute__((ext_vector_type(4))) float f32x4;

__device__ __forceinline__ unsigned int pack_bf16x2(float a, float b) {
    __hip_bfloat16 ha = __float2bfloat16(a);
    __hip_bfloat16 hb = __float2bfloat16(b);
    unsigned short ua, ub;
    __builtin_memcpy(&ua, &ha, 2);
    __builtin_memcpy(&ub, &hb, 2);
    return (unsigned int)ua | ((unsigned int)ub << 16);
}

__device__ __forceinline__ unsigned short bf16bits(float a) {
    __hip_bfloat16 h = __float2bfloat16(a);
    unsigned short u;
    __builtin_memcpy(&u, &h, 2);
    return u;
}

// out[b][v][t] = bias[t][v]   (atomic-fallback path only)
__global__ void init_out_kernel(float* __restrict__ out, const float* __restrict__ bias) {
    int i = blockIdx.x * 256 + threadIdx.x;
    if (i >= (int)OUTELEMS) return;
    int r = i % NCOLS;
    int v = r / L1C;
    int t = r - v * L1C;
    out[i] = bias[t * VC + v];
}

// X[s][b][w] = bf16(emb[src[b,s], w]), linear layout
__global__ void build_x_kernel(const int* __restrict__ src, const float* __restrict__ emb,
                               unsigned short* __restrict__ X) {
    const int s = blockIdx.x;
    const int b = threadIdx.x >> 1;
    const int half = threadIdx.x & 1;
    const int tok = src[b * L1C + s];
    const float2* e = (const float2*)(emb + tok * EMBC + half * 32);
    unsigned int* row = (unsigned int*)(X + ((size_t)s * BC + b) * EMBC) + half * 16;
#pragma unroll
    for (int i = 0; i < 16; ++i) {
        float2 f = e[i];
        row[i] = pack_bf16x2(f.x, f.y);
    }
}

// Per (n-tile, s-chunk) block: C[128 x 64] = sum_{s in chunk, s>=t} X_s(128x64) @ W_s(64x64)
// Register-diet structure (no A-prefetch set) -> VGPR<=128 -> 4 blocks/CU residency;
// A issued BEFORE W each iter so the MFMA vmcnt-wait keeps the W prefetch in flight.
// XCD tile-grouping swizzle: consecutive tiles of a chunk share an XCD (L2/DRAM locality).
template <bool PARTIAL>
__global__ __launch_bounds__(256, 4) void gemm_tril_kernel(
    const float* __restrict__ Wt, const unsigned short* __restrict__ X,
    void* __restrict__ outp, int CS) {
    // bijective XCD grouping over 49 tiles: q=6, r=1 (m204 form)
    const int xb = blockIdx.x;
    const int xcd = xb & 7;
    const int pos = xb >> 3;
    const int tile = ((xcd == 0) ? 0 : (7 + (xcd - 1) * 6)) + pos;

    const int chunk = blockIdx.y;
    const int n0 = tile * NTC;
    const int s0 = chunk * CS;
    const int sEnd = min(s0 + CS, L1C);
    const int sBeg = max(s0, n0 / VC);
    if (sBeg >= sEnd) return;  // dead block; reduce skips these chunks

    __shared__ __align__(16) unsigned short Blds[2][NTC * EMBC];  // 2 x 8KB

    const int tid = threadIdx.x;
    const int wid = tid >> 6;
    const int lane = tid & 63;
    const int l15 = lane & 15;
    const int h = lane >> 4;

    const int n = n0 + lane;
    const int tcol = n / VC;  // pad columns (n>=NCOLS) -> tcol>=513 -> always masked
    const size_t nsafe = (n < NCOLS) ? (size_t)n : (size_t)(NCOLS - 1);
    const int wrow0 = wid * 16;
    const int wswz = (lane & 7) << 4;

    f32x4 acc[2][4];
#pragma unroll
    for (int i = 0; i < 2; ++i)
#pragma unroll
        for (int j = 0; j < 4; ++j) acc[i][j] = f32x4{0.f, 0.f, 0.f, 0.f};

#define ISSUEW(ss, farr)                                                         \
    {                                                                            \
        const int scl_ = ((ss) < L1C) ? (ss) : (L1C - 1);                        \
        const float* wb_ = Wt + ((size_t)scl_ * EMBC + wrow0) * NCOLS + nsafe;   \
        _Pragma("unroll") for (int u_ = 0; u_ < 16; ++u_)                        \
            farr[u_] = wb_[(size_t)u_ * NCOLS];                                  \
    }

#define PACKW(ss, farr, buf)                                                     \
    {                                                                            \
        const bool act_ = (tcol <= (ss));                                        \
        char* dr_ = (char*)Blds[buf] + lane * 128;                               \
        _Pragma("unroll") for (int u_ = 0; u_ < 4; ++u_) {                       \
            float g0 = act_ ? farr[u_ * 4 + 0] : 0.f;                            \
            float g1 = act_ ? farr[u_ * 4 + 1] : 0.f;                            \
            float g2 = act_ ? farr[u_ * 4 + 2] : 0.f;                            \
            float g3 = act_ ? farr[u_ * 4 + 3] : 0.f;                            \
            uint2 pk_ = make_uint2(pack_bf16x2(g0, g1), pack_bf16x2(g2, g3));    \
            *(uint2*)(dr_ + ((2 * (wrow0 + u_ * 4)) ^ wswz)) = pk_;              \
        }                                                                        \
    }

#define ISSUEA(ss, aarr)                                                             \
    {                                                                                \
        const unsigned short* xr_ = X + (size_t)(ss) * (BC * EMBC);                  \
        aarr[0] = *(const short8*)(xr_ + (wid * 32 + l15) * EMBC + h * 8);           \
        aarr[1] = *(const short8*)(xr_ + (wid * 32 + l15) * EMBC + 32 + h * 8);      \
        aarr[2] = *(const short8*)(xr_ + (wid * 32 + 16 + l15) * EMBC + h * 8);      \
        aarr[3] = *(const short8*)(xr_ + (wid * 32 + 16 + l15) * EMBC + 32 + h * 8); \
    }

#define MFMASTEP(aarr, buf)                                                                              \
    {                                                                                                    \
        _Pragma("unroll") for (int kk_ = 0; kk_ < 2; ++kk_) {                                            \
            const int foff_ = (kk_ * 64 + h * 16) ^ ((l15 & 7) << 4);                                    \
            _Pragma("unroll") for (int nt_ = 0; nt_ < 4; ++nt_) {                                        \
                short8 bb_ = *(const short8*)((const char*)Blds[buf] + (nt_ * 16 + l15) * 128 + foff_);  \
                acc[0][nt_] = __builtin_amdgcn_mfma_f32_16x16x32_bf16(aarr[kk_], bb_, acc[0][nt_], 0, 0, 0);     \
                acc[1][nt_] = __builtin_amdgcn_mfma_f32_16x16x32_bf16(aarr[2 + kk_], bb_, acc[1][nt_], 0, 0, 0); \
            }                                                                                            \
        }                                                                                                \
    }

    {
        float fW0[16], fW1[16];
        short8 aC[4];
        // prologue: stage B(sBeg) via fW1's storage; 1-ahead W prefetch into fW0
        ISSUEW(sBeg, fW1);
        PACKW(sBeg, fW1, 0);
        ISSUEW(sBeg + 1, fW0);
        __syncthreads();

        int s = sBeg, cur = 0;
        while (true) {
            // even iter: A first (so MFMA wait leaves W in flight), then W(s+2)
            ISSUEA(s, aC);
            ISSUEW(s + 2, fW1);
            MFMASTEP(aC, cur);
            PACKW(s + 1, fW0, cur ^ 1);
            __syncthreads();
            cur ^= 1;
            if (++s >= sEnd) break;

            // odd iter: consume fW1
            ISSUEA(s, aC);
            ISSUEW(s + 2, fW0);
            MFMASTEP(aC, cur);
            PACKW(s + 1, fW1, cur ^ 1);
            __syncthreads();
            cur ^= 1;
            if (++s >= sEnd) break;
        }
    }

    // epilogue — C/D layout (verified): col = l15 (n), row-in-16 = h*4 + reg
#pragma unroll
    for (int nt = 0; nt < 4; ++nt) {
        const int nn = n0 + nt * 16 + l15;
        if (nn >= NCOLS) continue;
        if (PARTIAL) {
            unsigned short* dst = (unsigned short*)outp + (size_t)chunk * OUTELEMS;
#pragma unroll
            for (int ms = 0; ms < 2; ++ms)
#pragma unroll
                for (int r = 0; r < 4; ++r) {
                    const int bi = wid * 32 + ms * 16 + h * 4 + r;
                    dst[(size_t)bi * NCOLS + nn] = bf16bits(acc[ms][nt][r]);
                }
        } else {
            float* dst = (float*)outp;
            const int t = nn / VC;
            const int v = nn - t * VC;
            const size_t obase = (size_t)v * L1C + t;
#pragma unroll
            for (int ms = 0; ms < 2; ++ms)
#pragma unroll
                for (int r = 0; r < 4; ++r) {
                    const int bi = wid * 32 + ms * 16 + h * 4 + r;
                    atomicAdd(dst + (size_t)bi * NCOLS + obase, acc[ms][nt][r]);
                }
        }
    }
#undef ISSUEW
#undef PACKW
#undef ISSUEA
#undef MFMASTEP
}

// out[b][v][t] = bias[n] + sum_{c>=cfirst(tile(n))} bf16 partial[c][b][n],  n = t*6+v
__global__ void reduce_kernel(const unsigned short* __restrict__ partial,
                              const float* __restrict__ bias,
                              float* __restrict__ out, int nchunks, int CS) {
    int i4 = blockIdx.x * 256 + threadIdx.x;
    if (i4 >= (int)(OUTELEMS / 4)) return;
    const size_t base = (size_t)i4 * 4;
    float sum[4];
    int cf[4];
    int cmin = 1 << 30;
#pragma unroll
    for (int j = 0; j < 4; ++j) {
        int idx = (int)base + j;
        int nn = idx % NCOLS;
        sum[j] = bias[nn];
        int tl = nn >> 6;              // tile = nn / NTC (NTC=64)
        int tmin = (tl << 6) / VC;     // first live s for this tile
        cf[j] = tmin / CS;             // first live chunk (matches gemm's sBeg rule)
        cmin = min(cmin, cf[j]);
    }
    for (int c = cmin; c < nchunks; ++c) {
        const ushort4 p = *(const ushort4*)(partial + (size_t)c * OUTELEMS + base);
        unsigned int u0 = (unsigned int)p.x << 16, u1 = (unsigned int)p.y << 16;
        unsigned int u2 = (unsigned int)p.z << 16, u3 = (unsigned int)p.w << 16;
        float f0, f1, f2, f3;
        __builtin_memcpy(&f0, &u0, 4);
        __builtin_memcpy(&f1, &u1, 4);
        __builtin_memcpy(&f2, &u2, 4);
        __builtin_memcpy(&f3, &u3, 4);
        if (c >= cf[0]) sum[0] += f0;
        if (c >= cf[1]) sum[1] += f1;
        if (c >= cf[2]) sum[2] += f2;
        if (c >= cf[3]) sum[3] += f3;
    }
#pragma unroll
    for (int j = 0; j < 4; ++j) {
        int idx = (int)base + j;
        int b = idx / NCOLS;
        int nn = idx - b * NCOLS;
        int t = nn / VC;
        int v = nn - t * VC;
        out[(size_t)b * NCOLS + (size_t)v * L1C + t] = sum[j];
    }
}

extern "C" void kernel_launch(void* const* d_in, const int* in_sizes, int n_in,
                              void* d_out, int out_size, void* d_ws, size_t ws_size,
                              hipStream_t stream) {
    const int* src = (const int*)d_in[0];
    const float* emb = (const float*)d_in[1];
    const float* wt = (const float*)d_in[2];
    const float* bias = (const float*)d_in[3];
    float* out = (float*)d_out;
    unsigned short* X = (unsigned short*)d_ws;

    build_x_kernel<<<L1C, 256, 0, stream>>>(src, emb, X);

    if (ws_size >= XBYTES + (size_t)NCHUNK * PARTBYTES) {
        unsigned short* partial = (unsigned short*)((char*)d_ws + XBYTES);
        dim3 grid(NTILES, NCHUNK);   // blockIdx.x is XCD-swizzled inside the kernel
        gemm_tril_kernel<true><<<grid, 256, 0, stream>>>(wt, X, (void*)partial, CSC);
        reduce_kernel<<<(int)((OUTELEMS / 4 + 255) / 256), 256, 0, stream>>>(partial, bias, out, NCHUNK, CSC);
    } else if (ws_size >= XBYTES + 2 * PARTBYTES) {
        int nchunks = (int)((ws_size - XBYTES) / PARTBYTES);
        if (nchunks > NCHUNK) nchunks = NCHUNK;
        int CS = (L1C + nchunks - 1) / nchunks;
        nchunks = (L1C + CS - 1) / CS;
        unsigned short* partial = (unsigned short*)((char*)d_ws + XBYTES);
        dim3 grid(NTILES, nchunks);
        gemm_tril_kernel<true><<<grid, 256, 0, stream>>>(wt, X, (void*)partial, CS);
        reduce_kernel<<<(int)((OUTELEMS / 4 + 255) / 256), 256, 0, stream>>>(partial, bias, out, nchunks, CS);
    } else {
        init_out_kernel<<<(int)((OUTELEMS + 255) / 256), 256, 0, stream>>>(out, bias);
        dim3 grid(NTILES, 17);
        gemm_tril_kernel<false><<<grid, 256, 0, stream>>>(wt, X, (void*)out, 31);
    }
}

// Round 12
// 83.678 us; speedup vs baseline: 7.9479x; 1.0335x over previous
//
#include <hip/hip_runtime.h>
#include <hip/hip_bf16.h>

// Problem constants
#define L1C 513
#define EMBC 64
#define VC 6
#define BC 128
#define NCOLS (L1C * VC)                  // 3078
#define NTC 64                            // n-columns per block tile
#define NTILES ((NCOLS + NTC - 1) / NTC)  // 49
#define CSC 14                            // s per chunk: ~916 live blocks ~= 3.6/CU (fits 4/CU residency)
#define NCHUNK ((L1C + CSC - 1) / CSC)    // 37

#define XELEMS ((size_t)L1C * BC * EMBC)
#define XBYTES (XELEMS * 2)               // 8,404,992
#define OUTELEMS ((size_t)BC * NCOLS)     // 393,984
#define PARTBYTES (OUTELEMS * 2)          // bf16 partials per chunk

typedef __attribute__((ext_vector_type(8))) short short8;
typedef __attribute__((ext_vector_type(4))) float f32x4;

__device__ __forceinline__ unsigned int pack_bf16x2(float a, float b) {
    __hip_bfloat16 ha = __float2bfloat16(a);
    __hip_bfloat16 hb = __float2bfloat16(b);
    unsigned short ua, ub;
    __builtin_memcpy(&ua, &ha, 2);
    __builtin_memcpy(&ub, &hb, 2);
    return (unsigned int)ua | ((unsigned int)ub << 16);
}

__device__ __forceinline__ unsigned short bf16bits(float a) {
    __hip_bfloat16 h = __float2bfloat16(a);
    unsigned short u;
    __builtin_memcpy(&u, &h, 2);
    return u;
}

// out[b][v][t] = bias[t][v]   (atomic-fallback path only)
__global__ void init_out_kernel(float* __restrict__ out, const float* __restrict__ bias) {
    int i = blockIdx.x * 256 + threadIdx.x;
    if (i >= (int)OUTELEMS) return;
    int r = i % NCOLS;
    int v = r / L1C;
    int t = r - v * L1C;
    out[i] = bias[t * VC + v];
}

// X[s][b][w] = bf16(emb[src[b,s], w]), linear layout
__global__ void build_x_kernel(const int* __restrict__ src, const float* __restrict__ emb,
                               unsigned short* __restrict__ X) {
    const int s = blockIdx.x;
    const int b = threadIdx.x >> 1;
    const int half = threadIdx.x & 1;
    const int tok = src[b * L1C + s];
    const float2* e = (const float2*)(emb + tok * EMBC + half * 32);
    unsigned int* row = (unsigned int*)(X + ((size_t)s * BC + b) * EMBC) + half * 16;
#pragma unroll
    for (int i = 0; i < 16; ++i) {
        float2 f = e[i];
        row[i] = pack_bf16x2(f.x, f.y);
    }
}

// Per (n-tile, s-chunk) block: C[128 x 64] = sum_{s in chunk, s>=t} X_s(128x64) @ W_s(64x64)
// r11 structure + (a) no W prefetch past sEnd (kills 2/16 over-fetch),
// (b) 8B-granular LDS swizzle (row&15)<<3: write/read conflicts 8-way -> 4-way.
template <bool PARTIAL>
__global__ __launch_bounds__(256, 4) void gemm_tril_kernel(
    const float* __restrict__ Wt, const unsigned short* __restrict__ X,
    void* __restrict__ outp, int CS) {
    // bijective XCD grouping over 49 tiles: q=6, r=1 (m204 form)
    const int xb = blockIdx.x;
    const int xcd = xb & 7;
    const int pos = xb >> 3;
    const int tile = ((xcd == 0) ? 0 : (7 + (xcd - 1) * 6)) + pos;

    const int chunk = blockIdx.y;
    const int n0 = tile * NTC;
    const int s0 = chunk * CS;
    const int sEnd = min(s0 + CS, L1C);
    const int sBeg = max(s0, n0 / VC);
    if (sBeg >= sEnd) return;  // dead block; reduce skips these chunks

    __shared__ __align__(16) unsigned short Blds[2][NTC * EMBC];  // 2 x 8KB

    const int tid = threadIdx.x;
    const int wid = tid >> 6;
    const int lane = tid & 63;
    const int l15 = lane & 15;
    const int h = lane >> 4;

    const int n = n0 + lane;
    const int tcol = n / VC;  // pad columns (n>=NCOLS) -> tcol>=513 -> always masked
    const size_t nsafe = (n < NCOLS) ? (size_t)n : (size_t)(NCOLS - 1);
    const int wrow0 = wid * 16;

    f32x4 acc[2][4];
#pragma unroll
    for (int i = 0; i < 2; ++i)
#pragma unroll
        for (int j = 0; j < 4; ++j) acc[i][j] = f32x4{0.f, 0.f, 0.f, 0.f};

#define ISSUEW(ss, farr)                                                         \
    {                                                                            \
        const float* wb_ = Wt + ((size_t)(ss) * EMBC + wrow0) * NCOLS + nsafe;   \
        _Pragma("unroll") for (int u_ = 0; u_ < 16; ++u_)                        \
            farr[u_] = wb_[(size_t)u_ * NCOLS];                                  \
    }

// 8B-granular swizzle: logical byte col c of row r stored at c ^ ((r&15)<<3)
#define PACKW(ss, farr, buf)                                                     \
    {                                                                            \
        const bool act_ = (tcol <= (ss));                                        \
        char* dr_ = (char*)Blds[buf] + lane * 128;                               \
        const int sw_ = (lane & 15) << 3;                                        \
        _Pragma("unroll") for (int u_ = 0; u_ < 4; ++u_) {                       \
            float g0 = act_ ? farr[u_ * 4 + 0] : 0.f;                            \
            float g1 = act_ ? farr[u_ * 4 + 1] : 0.f;                            \
            float g2 = act_ ? farr[u_ * 4 + 2] : 0.f;                            \
            float g3 = act_ ? farr[u_ * 4 + 3] : 0.f;                            \
            uint2 pk_ = make_uint2(pack_bf16x2(g0, g1), pack_bf16x2(g2, g3));    \
            *(uint2*)(dr_ + ((wid * 32 + u_ * 8) ^ sw_)) = pk_;                  \
        }                                                                        \
    }

#define ISSUEA(ss, aarr)                                                             \
    {                                                                                \
        const unsigned short* xr_ = X + (size_t)(ss) * (BC * EMBC);                  \
        aarr[0] = *(const short8*)(xr_ + (wid * 32 + l15) * EMBC + h * 8);           \
        aarr[1] = *(const short8*)(xr_ + (wid * 32 + l15) * EMBC + 32 + h * 8);      \
        aarr[2] = *(const short8*)(xr_ + (wid * 32 + 16 + l15) * EMBC + h * 8);      \
        aarr[3] = *(const short8*)(xr_ + (wid * 32 + 16 + l15) * EMBC + 32 + h * 8); \
    }

// B-frag read: two ds_read_b64 per fragment (8B swizzle breaks 16B alignment)
#define MFMASTEP(aarr, buf)                                                                          \
    {                                                                                                \
        const int sw_ = l15 << 3;                                                                    \
        _Pragma("unroll") for (int kk_ = 0; kk_ < 2; ++kk_) {                                        \
            _Pragma("unroll") for (int nt_ = 0; nt_ < 4; ++nt_) {                                    \
                const char* rb_ = (const char*)Blds[buf] + (nt_ * 16 + l15) * 128;                   \
                const int c0_ = (kk_ * 64 + h * 16) ^ sw_;                                           \
                short8 bb_;                                                                          \
                __builtin_memcpy(&bb_, rb_ + c0_, 8);                                                \
                __builtin_memcpy((char*)&bb_ + 8, rb_ + (c0_ ^ 8), 8);                               \
                acc[0][nt_] = __builtin_amdgcn_mfma_f32_16x16x32_bf16(aarr[kk_], bb_, acc[0][nt_], 0, 0, 0);     \
                acc[1][nt_] = __builtin_amdgcn_mfma_f32_16x16x32_bf16(aarr[2 + kk_], bb_, acc[1][nt_], 0, 0, 0); \
            }                                                                                        \
        }                                                                                            \
    }

    {
        float fW0[16], fW1[16];
        short8 aC[4];
        // prologue: stage B(sBeg) via fW1's storage; 1-ahead W prefetch only if needed
        ISSUEW(sBeg, fW1);
        PACKW(sBeg, fW1, 0);
        if (sBeg + 1 < sEnd) ISSUEW(sBeg + 1, fW0);
        __syncthreads();

        int s = sBeg, cur = 0;
        while (true) {
            // even iter: A first (MFMA wait leaves W in flight); no W fetch past sEnd
            ISSUEA(s, aC);
            if (s + 2 < sEnd) ISSUEW(s + 2, fW1);
            MFMASTEP(aC, cur);
            if (s + 1 < sEnd) PACKW(s + 1, fW0, cur ^ 1);
            __syncthreads();
            cur ^= 1;
            if (++s >= sEnd) break;

            // odd iter: consume fW1
            ISSUEA(s, aC);
            if (s + 2 < sEnd) ISSUEW(s + 2, fW0);
            MFMASTEP(aC, cur);
            if (s + 1 < sEnd) PACKW(s + 1, fW1, cur ^ 1);
            __syncthreads();
            cur ^= 1;
            if (++s >= sEnd) break;
        }
    }

    // epilogue — C/D layout (verified): col = l15 (n), row-in-16 = h*4 + reg
#pragma unroll
    for (int nt = 0; nt < 4; ++nt) {
        const int nn = n0 + nt * 16 + l15;
        if (nn >= NCOLS) continue;
        if (PARTIAL) {
            unsigned short* dst = (unsigned short*)outp + (size_t)chunk * OUTELEMS;
#pragma unroll
            for (int ms = 0; ms < 2; ++ms)
#pragma unroll
                for (int r = 0; r < 4; ++r) {
                    const int bi = wid * 32 + ms * 16 + h * 4 + r;
                    dst[(size_t)bi * NCOLS + nn] = bf16bits(acc[ms][nt][r]);
                }
        } else {
            float* dst = (float*)outp;
            const int t = nn / VC;
            const int v = nn - t * VC;
            const size_t obase = (size_t)v * L1C + t;
#pragma unroll
            for (int ms = 0; ms < 2; ++ms)
#pragma unroll
                for (int r = 0; r < 4; ++r) {
                    const int bi = wid * 32 + ms * 16 + h * 4 + r;
                    atomicAdd(dst + (size_t)bi * NCOLS + obase, acc[ms][nt][r]);
                }
        }
    }
#undef ISSUEW
#undef PACKW
#undef ISSUEA
#undef MFMASTEP
}

// out[b][v][t] = bias[n] + sum_{c>=cfirst(tile(n))} bf16 partial[c][b][n],  n = t*6+v
__global__ void reduce_kernel(const unsigned short* __restrict__ partial,
                              const float* __restrict__ bias,
                              float* __restrict__ out, int nchunks, int CS) {
    int i4 = blockIdx.x * 256 + threadIdx.x;
    if (i4 >= (int)(OUTELEMS / 4)) return;
    const size_t base = (size_t)i4 * 4;
    float sum[4];
    int cf[4];
    int cmin = 1 << 30;
#pragma unroll
    for (int j = 0; j < 4; ++j) {
        int idx = (int)base + j;
        int nn = idx % NCOLS;
        sum[j] = bias[nn];
        int tl = nn >> 6;              // tile = nn / NTC (NTC=64)
        int tmin = (tl << 6) / VC;     // first live s for this tile
        cf[j] = tmin / CS;             // first live chunk (matches gemm's sBeg rule)
        cmin = min(cmin, cf[j]);
    }
    for (int c = cmin; c < nchunks; ++c) {
        const ushort4 p = *(const ushort4*)(partial + (size_t)c * OUTELEMS + base);
        unsigned int u0 = (unsigned int)p.x << 16, u1 = (unsigned int)p.y << 16;
        unsigned int u2 = (unsigned int)p.z << 16, u3 = (unsigned int)p.w << 16;
        float f0, f1, f2, f3;
        __builtin_memcpy(&f0, &u0, 4);
        __builtin_memcpy(&f1, &u1, 4);
        __builtin_memcpy(&f2, &u2, 4);
        __builtin_memcpy(&f3, &u3, 4);
        if (c >= cf[0]) sum[0] += f0;
        if (c >= cf[1]) sum[1] += f1;
        if (c >= cf[2]) sum[2] += f2;
        if (c >= cf[3]) sum[3] += f3;
    }
#pragma unroll
    for (int j = 0; j < 4; ++j) {
        int idx = (int)base + j;
        int b = idx / NCOLS;
        int nn = idx - b * NCOLS;
        int t = nn / VC;
        int v = nn - t * VC;
        out[(size_t)b * NCOLS + (size_t)v * L1C + t] = sum[j];
    }
}

extern "C" void kernel_launch(void* const* d_in, const int* in_sizes, int n_in,
                              void* d_out, int out_size, void* d_ws, size_t ws_size,
                              hipStream_t stream) {
    const int* src = (const int*)d_in[0];
    const float* emb = (const float*)d_in[1];
    const float* wt = (const float*)d_in[2];
    const float* bias = (const float*)d_in[3];
    float* out = (float*)d_out;
    unsigned short* X = (unsigned short*)d_ws;

    build_x_kernel<<<L1C, 256, 0, stream>>>(src, emb, X);

    if (ws_size >= XBYTES + (size_t)NCHUNK * PARTBYTES) {
        unsigned short* partial = (unsigned short*)((char*)d_ws + XBYTES);
        dim3 grid(NTILES, NCHUNK);   // blockIdx.x is XCD-swizzled inside the kernel
        gemm_tril_kernel<true><<<grid, 256, 0, stream>>>(wt, X, (void*)partial, CSC);
        reduce_kernel<<<(int)((OUTELEMS / 4 + 255) / 256), 256, 0, stream>>>(partial, bias, out, NCHUNK, CSC);
    } else if (ws_size >= XBYTES + 2 * PARTBYTES) {
        int nchunks = (int)((ws_size - XBYTES) / PARTBYTES);
        if (nchunks > NCHUNK) nchunks = NCHUNK;
        int CS = (L1C + nchunks - 1) / nchunks;
        nchunks = (L1C + CS - 1) / CS;
        unsigned short* partial = (unsigned short*)((char*)d_ws + XBYTES);
        dim3 grid(NTILES, nchunks);
        gemm_tril_kernel<true><<<grid, 256, 0, stream>>>(wt, X, (void*)partial, CS);
        reduce_kernel<<<(int)((OUTELEMS / 4 + 255) / 256), 256, 0, stream>>>(partial, bias, out, nchunks, CS);
    } else {
        init_out_kernel<<<(int)((OUTELEMS + 255) / 256), 256, 0, stream>>>(out, bias);
        dim3 grid(NTILES, 17);
        gemm_tril_kernel<false><<<grid, 256, 0, stream>>>(wt, X, (void*)out, 31);
    }
}

// Round 13
// 82.889 us; speedup vs baseline: 8.0236x; 1.0095x over previous
//
#include <hip/hip_runtime.h>
#include <hip/hip_bf16.h>

// Problem constants
#define L1C 513
#define EMBC 64
#define VC 6
#define BC 128
#define NCOLS (L1C * VC)                  // 3078
#define NTC 64                            // n-columns per block tile
#define NTILES ((NCOLS + NTC - 1) / NTC)  // 49
#define CSC 13                            // s per chunk: ~1000 live blocks ~= full 4/CU residency
#define NCHUNK ((L1C + CSC - 1) / CSC)    // 40

#define XELEMS ((size_t)L1C * BC * EMBC)
#define XBYTES (XELEMS * 2)               // 8,404,992
#define OUTELEMS ((size_t)BC * NCOLS)     // 393,984
#define PARTBYTES (OUTELEMS * 2)          // bf16 partials per chunk

typedef __attribute__((ext_vector_type(8))) short short8;
typedef __attribute__((ext_vector_type(4))) float f32x4;

__device__ __forceinline__ unsigned int pack_bf16x2(float a, float b) {
    __hip_bfloat16 ha = __float2bfloat16(a);
    __hip_bfloat16 hb = __float2bfloat16(b);
    unsigned short ua, ub;
    __builtin_memcpy(&ua, &ha, 2);
    __builtin_memcpy(&ub, &hb, 2);
    return (unsigned int)ua | ((unsigned int)ub << 16);
}

__device__ __forceinline__ unsigned short bf16bits(float a) {
    __hip_bfloat16 h = __float2bfloat16(a);
    unsigned short u;
    __builtin_memcpy(&u, &h, 2);
    return u;
}

// out[b][v][t] = bias[t][v]   (atomic-fallback path only)
__global__ void init_out_kernel(float* __restrict__ out, const float* __restrict__ bias) {
    int i = blockIdx.x * 256 + threadIdx.x;
    if (i >= (int)OUTELEMS) return;
    int r = i % NCOLS;
    int v = r / L1C;
    int t = r - v * L1C;
    out[i] = bias[t * VC + v];
}

// X[s][b][w] = bf16(emb[src[b,s], w]), linear layout
__global__ void build_x_kernel(const int* __restrict__ src, const float* __restrict__ emb,
                               unsigned short* __restrict__ X) {
    const int s = blockIdx.x;
    const int b = threadIdx.x >> 1;
    const int half = threadIdx.x & 1;
    const int tok = src[b * L1C + s];
    const float2* e = (const float2*)(emb + tok * EMBC + half * 32);
    unsigned int* row = (unsigned int*)(X + ((size_t)s * BC + b) * EMBC) + half * 16;
#pragma unroll
    for (int i = 0; i < 16; ++i) {
        float2 f = e[i];
        row[i] = pack_bf16x2(f.x, f.y);
    }
}

// Per (n-tile, s-chunk) block: C[128 x 64] = sum_{s in chunk, s>=t} X_s(128x64) @ W_s(64x64)
// r12 structure + SYNCB (lgkmcnt-only barrier: W prefetches stay in flight across
// the barrier -> sustained ~20KB/CU in-flight instead of drain-collapsed ~half).
template <bool PARTIAL>
__global__ __launch_bounds__(256, 4) void gemm_tril_kernel(
    const float* __restrict__ Wt, const unsigned short* __restrict__ X,
    void* __restrict__ outp, int CS) {
    // bijective XCD grouping over 49 tiles: q=6, r=1 (m204 form)
    const int xb = blockIdx.x;
    const int xcd = xb & 7;
    const int pos = xb >> 3;
    const int tile = ((xcd == 0) ? 0 : (7 + (xcd - 1) * 6)) + pos;

    const int chunk = blockIdx.y;
    const int n0 = tile * NTC;
    const int s0 = chunk * CS;
    const int sEnd = min(s0 + CS, L1C);
    const int sBeg = max(s0, n0 / VC);
    if (sBeg >= sEnd) return;  // dead block; reduce skips these chunks

    __shared__ __align__(16) unsigned short Blds[2][NTC * EMBC];  // 2 x 8KB

    const int tid = threadIdx.x;
    const int wid = tid >> 6;
    const int lane = tid & 63;
    const int l15 = lane & 15;
    const int h = lane >> 4;

    const int n = n0 + lane;
    const int tcol = n / VC;  // pad columns (n>=NCOLS) -> tcol>=513 -> always masked
    const size_t nsafe = (n < NCOLS) ? (size_t)n : (size_t)(NCOLS - 1);
    const int wrow0 = wid * 16;

    f32x4 acc[2][4];
#pragma unroll
    for (int i = 0; i < 2; ++i)
#pragma unroll
        for (int j = 0; j < 4; ++j) acc[i][j] = f32x4{0.f, 0.f, 0.f, 0.f};

// Raw barrier: drain LDS ops only; global loads stay in flight (counted vmcnt
// waits auto-inserted at register use). Correctness-proven in round 5.
#define SYNCB()                                                \
    {                                                          \
        __builtin_amdgcn_sched_barrier(0);                     \
        asm volatile("s_waitcnt lgkmcnt(0)" ::: "memory");     \
        __builtin_amdgcn_s_barrier();                          \
        __builtin_amdgcn_sched_barrier(0);                     \
    }

#define ISSUEW(ss, farr)                                                         \
    {                                                                            \
        const float* wb_ = Wt + ((size_t)(ss) * EMBC + wrow0) * NCOLS + nsafe;   \
        _Pragma("unroll") for (int u_ = 0; u_ < 16; ++u_)                        \
            farr[u_] = wb_[(size_t)u_ * NCOLS];                                  \
    }

// 8B-granular swizzle: logical byte col c of row r stored at c ^ ((r&15)<<3)
#define PACKW(ss, farr, buf)                                                     \
    {                                                                            \
        const bool act_ = (tcol <= (ss));                                        \
        char* dr_ = (char*)Blds[buf] + lane * 128;                               \
        const int sw_ = (lane & 15) << 3;                                        \
        _Pragma("unroll") for (int u_ = 0; u_ < 4; ++u_) {                       \
            float g0 = act_ ? farr[u_ * 4 + 0] : 0.f;                            \
            float g1 = act_ ? farr[u_ * 4 + 1] : 0.f;                            \
            float g2 = act_ ? farr[u_ * 4 + 2] : 0.f;                            \
            float g3 = act_ ? farr[u_ * 4 + 3] : 0.f;                            \
            uint2 pk_ = make_uint2(pack_bf16x2(g0, g1), pack_bf16x2(g2, g3));    \
            *(uint2*)(dr_ + ((wid * 32 + u_ * 8) ^ sw_)) = pk_;                  \
        }                                                                        \
    }

#define ISSUEA(ss, aarr)                                                             \
    {                                                                                \
        const unsigned short* xr_ = X + (size_t)(ss) * (BC * EMBC);                  \
        aarr[0] = *(const short8*)(xr_ + (wid * 32 + l15) * EMBC + h * 8);           \
        aarr[1] = *(const short8*)(xr_ + (wid * 32 + l15) * EMBC + 32 + h * 8);      \
        aarr[2] = *(const short8*)(xr_ + (wid * 32 + 16 + l15) * EMBC + h * 8);      \
        aarr[3] = *(const short8*)(xr_ + (wid * 32 + 16 + l15) * EMBC + 32 + h * 8); \
    }

// B-frag read: two ds_read_b64 per fragment (8B swizzle)
#define MFMASTEP(aarr, buf)                                                                          \
    {                                                                                                \
        const int sw_ = l15 << 3;                                                                    \
        _Pragma("unroll") for (int kk_ = 0; kk_ < 2; ++kk_) {                                        \
            _Pragma("unroll") for (int nt_ = 0; nt_ < 4; ++nt_) {                                    \
                const char* rb_ = (const char*)Blds[buf] + (nt_ * 16 + l15) * 128;                   \
                const int c0_ = (kk_ * 64 + h * 16) ^ sw_;                                           \
                short8 bb_;                                                                          \
                __builtin_memcpy(&bb_, rb_ + c0_, 8);                                                \
                __builtin_memcpy((char*)&bb_ + 8, rb_ + (c0_ ^ 8), 8);                               \
                acc[0][nt_] = __builtin_amdgcn_mfma_f32_16x16x32_bf16(aarr[kk_], bb_, acc[0][nt_], 0, 0, 0);     \
                acc[1][nt_] = __builtin_amdgcn_mfma_f32_16x16x32_bf16(aarr[2 + kk_], bb_, acc[1][nt_], 0, 0, 0); \
            }                                                                                        \
        }                                                                                            \
    }

    {
        float fW0[16], fW1[16];
        short8 aC[4];
        // prologue: stage B(sBeg) via fW1's storage; 1-ahead W prefetch only if needed
        ISSUEW(sBeg, fW1);
        PACKW(sBeg, fW1, 0);
        if (sBeg + 1 < sEnd) ISSUEW(sBeg + 1, fW0);
        SYNCB();

        int s = sBeg, cur = 0;
        while (true) {
            // even iter: A first (MFMA wait leaves W in flight); no W fetch past sEnd
            ISSUEA(s, aC);
            if (s + 2 < sEnd) ISSUEW(s + 2, fW1);
            MFMASTEP(aC, cur);
            if (s + 1 < sEnd) PACKW(s + 1, fW0, cur ^ 1);
            SYNCB();
            cur ^= 1;
            if (++s >= sEnd) break;

            // odd iter: consume fW1
            ISSUEA(s, aC);
            if (s + 2 < sEnd) ISSUEW(s + 2, fW0);
            MFMASTEP(aC, cur);
            if (s + 1 < sEnd) PACKW(s + 1, fW1, cur ^ 1);
            SYNCB();
            cur ^= 1;
            if (++s >= sEnd) break;
        }
    }

    // epilogue — C/D layout (verified): col = l15 (n), row-in-16 = h*4 + reg
#pragma unroll
    for (int nt = 0; nt < 4; ++nt) {
        const int nn = n0 + nt * 16 + l15;
        if (nn >= NCOLS) continue;
        if (PARTIAL) {
            unsigned short* dst = (unsigned short*)outp + (size_t)chunk * OUTELEMS;
#pragma unroll
            for (int ms = 0; ms < 2; ++ms)
#pragma unroll
                for (int r = 0; r < 4; ++r) {
                    const int bi = wid * 32 + ms * 16 + h * 4 + r;
                    dst[(size_t)bi * NCOLS + nn] = bf16bits(acc[ms][nt][r]);
                }
        } else {
            float* dst = (float*)outp;
            const int t = nn / VC;
            const int v = nn - t * VC;
            const size_t obase = (size_t)v * L1C + t;
#pragma unroll
            for (int ms = 0; ms < 2; ++ms)
#pragma unroll
                for (int r = 0; r < 4; ++r) {
                    const int bi = wid * 32 + ms * 16 + h * 4 + r;
                    atomicAdd(dst + (size_t)bi * NCOLS + obase, acc[ms][nt][r]);
                }
        }
    }
#undef SYNCB
#undef ISSUEW
#undef PACKW
#undef ISSUEA
#undef MFMASTEP
}

// out[b][v][t] = bias[n] + sum_{c>=cfirst(tile(n))} bf16 partial[c][b][n],  n = t*6+v
__global__ void reduce_kernel(const unsigned short* __restrict__ partial,
                              const float* __restrict__ bias,
                              float* __restrict__ out, int nchunks, int CS) {
    int i4 = blockIdx.x * 256 + threadIdx.x;
    if (i4 >= (int)(OUTELEMS / 4)) return;
    const size_t base = (size_t)i4 * 4;
    float sum[4];
    int cf[4];
    int cmin = 1 << 30;
#pragma unroll
    for (int j = 0; j < 4; ++j) {
        int idx = (int)base + j;
        int nn = idx % NCOLS;
        sum[j] = bias[nn];
        int tl = nn >> 6;              // tile = nn / NTC (NTC=64)
        int tmin = (tl << 6) / VC;     // first live s for this tile
        cf[j] = tmin / CS;             // first live chunk (matches gemm's sBeg rule)
        cmin = min(cmin, cf[j]);
    }
    for (int c = cmin; c < nchunks; ++c) {
        const ushort4 p = *(const ushort4*)(partial + (size_t)c * OUTELEMS + base);
        unsigned int u0 = (unsigned int)p.x << 16, u1 = (unsigned int)p.y << 16;
        unsigned int u2 = (unsigned int)p.z << 16, u3 = (unsigned int)p.w << 16;
        float f0, f1, f2, f3;
        __builtin_memcpy(&f0, &u0, 4);
        __builtin_memcpy(&f1, &u1, 4);
        __builtin_memcpy(&f2, &u2, 4);
        __builtin_memcpy(&f3, &u3, 4);
        if (c >= cf[0]) sum[0] += f0;
        if (c >= cf[1]) sum[1] += f1;
        if (c >= cf[2]) sum[2] += f2;
        if (c >= cf[3]) sum[3] += f3;
    }
#pragma unroll
    for (int j = 0; j < 4; ++j) {
        int idx = (int)base + j;
        int b = idx / NCOLS;
        int nn = idx - b * NCOLS;
        int t = nn / VC;
        int v = nn - t * VC;
        out[(size_t)b * NCOLS + (size_t)v * L1C + t] = sum[j];
    }
}

extern "C" void kernel_launch(void* const* d_in, const int* in_sizes, int n_in,
                              void* d_out, int out_size, void* d_ws, size_t ws_size,
                              hipStream_t stream) {
    const int* src = (const int*)d_in[0];
    const float* emb = (const float*)d_in[1];
    const float* wt = (const float*)d_in[2];
    const float* bias = (const float*)d_in[3];
    float* out = (float*)d_out;
    unsigned short* X = (unsigned short*)d_ws;

    build_x_kernel<<<L1C, 256, 0, stream>>>(src, emb, X);

    if (ws_size >= XBYTES + (size_t)NCHUNK * PARTBYTES) {
        unsigned short* partial = (unsigned short*)((char*)d_ws + XBYTES);
        dim3 grid(NTILES, NCHUNK);   // blockIdx.x is XCD-swizzled inside the kernel
        gemm_tril_kernel<true><<<grid, 256, 0, stream>>>(wt, X, (void*)partial, CSC);
        reduce_kernel<<<(int)((OUTELEMS / 4 + 255) / 256), 256, 0, stream>>>(partial, bias, out, NCHUNK, CSC);
    } else if (ws_size >= XBYTES + 2 * PARTBYTES) {
        int nchunks = (int)((ws_size - XBYTES) / PARTBYTES);
        if (nchunks > NCHUNK) nchunks = NCHUNK;
        int CS = (L1C + nchunks - 1) / nchunks;
        nchunks = (L1C + CS - 1) / CS;
        unsigned short* partial = (unsigned short*)((char*)d_ws + XBYTES);
        dim3 grid(NTILES, nchunks);
        gemm_tril_kernel<true><<<grid, 256, 0, stream>>>(wt, X, (void*)partial, CS);
        reduce_kernel<<<(int)((OUTELEMS / 4 + 255) / 256), 256, 0, stream>>>(partial, bias, out, nchunks, CS);
    } else {
        init_out_kernel<<<(int)((OUTELEMS + 255) / 256), 256, 0, stream>>>(out, bias);
        dim3 grid(NTILES, 17);
        gemm_tril_kernel<false><<<grid, 256, 0, stream>>>(wt, X, (void*)out, 31);
    }
}